// Round 5
// baseline (288.080 us; speedup 1.0000x reference)
//
#include <hip/hip_runtime.h>
#include <hip/hip_bf16.h>
#include <hip/hip_cooperative_groups.h>
#include <cstdint>
#include <cmath>

namespace cg = cooperative_groups;

// Problem constants — inputs/outputs are fp32 (verified R1 vs R2).
#define T_SEQ 16384
#define DMODEL 512
#define NCHUNK 512        // scan chunks == coop grid size
#define LCHUNK 32         // T_SEQ / NCHUNK
#define XS_N   (T_SEQ * DMODEL)
#define W_N    (DMODEL * DMODEL)
#define N4_XS  (XS_N / 4)
#define N4_W   (W_N / 4)
#define N4_TOT (N4_XS + 3 * N4_W)

typedef __bf16 bf16x8 __attribute__((ext_vector_type(8)));
typedef float  f32x4  __attribute__((ext_vector_type(4)));

using bf16 = __hip_bfloat16;

__device__ __forceinline__ void load_lds16(const void* g, void* l) {
    __builtin_amdgcn_global_load_lds((const __attribute__((address_space(1))) void*)g,
                                     (__attribute__((address_space(3))) void*)l,
                                     16, 0, 0);
}

__device__ __forceinline__ unsigned short f2bf(float f) {
    union { float f; unsigned u; } v; v.f = f;
    const unsigned r = (v.u + 0x7FFFu + ((v.u >> 16) & 1u)) >> 16;
    return (unsigned short)r;
}
__device__ __forceinline__ float bf2f(unsigned short u) {
    union { unsigned u; float f; } v; v.u = ((unsigned)u) << 16;
    return v.f;
}

// ---------------------------------------------------------------------------
// Kernel 0: convert xs, Wz, Wh, Wo fp32 -> bf16 (vectorized x4)
// ---------------------------------------------------------------------------
__global__ __launch_bounds__(256) void k_convert(
    const float* __restrict__ xs, const float* __restrict__ Wz,
    const float* __restrict__ Wh, const float* __restrict__ Wo,
    bf16* __restrict__ xs_c, bf16* __restrict__ Wz_c,
    bf16* __restrict__ Wh_c, bf16* __restrict__ Wo_c)
{
    const int i = blockIdx.x * 256 + threadIdx.x;
    if (i >= N4_TOT) return;
    const float* src;
    bf16* dst;
    int o;
    if (i < N4_XS) { src = xs; dst = xs_c; o = i; }
    else {
        const int j = i - N4_XS;
        const int w = j >> 16;
        o = j & 65535;
        src = (w == 0) ? Wz : (w == 1) ? Wh : Wo;
        dst = (w == 0) ? Wz_c : (w == 1) ? Wh_c : Wo_c;
    }
    const float4 v = ((const float4*)src)[o];
    ushort4 r;
    r.x = f2bf(v.x); r.y = f2bf(v.y); r.z = f2bf(v.z); r.w = f2bf(v.w);
    ((ushort4*)dst)[o] = r;
}

// ---------------------------------------------------------------------------
// Kernel 1: fused dual GEMM; epilogue packs (a,b) as bf16 pair -> u32
// ---------------------------------------------------------------------------
__global__ __launch_bounds__(256, 2) void gemm_zh(
    const bf16* __restrict__ xs, const bf16* __restrict__ Wz, const float* __restrict__ bz,
    const bf16* __restrict__ Wh, const float* __restrict__ bh,
    unsigned int* __restrict__ ab_ws)
{
    __shared__ __bf16 As[128 * 64];
    __shared__ __bf16 Zs[128 * 64];
    __shared__ __bf16 Hs[128 * 64];

    const int tid  = threadIdx.x;
    const int bn   = blockIdx.x;
    const int bm   = blockIdx.y;
    const int lane = tid & 63;
    const int wave = tid >> 6;
    const int wm   = wave >> 1;
    const int wn   = wave & 1;

    f32x4 accz[4][4], acch[4][4];
    #pragma unroll
    for (int i = 0; i < 4; ++i)
        #pragma unroll
        for (int j = 0; j < 4; ++j) {
            accz[i][j] = (f32x4){0.f, 0.f, 0.f, 0.f};
            acch[i][j] = (f32x4){0.f, 0.f, 0.f, 0.f};
        }

    const int row0 = tid >> 3;
    const int k8   = tid & 7;

    const bf16* xg = xs + (size_t)(bm * 128) * DMODEL + k8 * 8;
    const bf16* zg = Wz + (size_t)(bn * 128) * DMODEL + k8 * 8;
    const bf16* hg = Wh + (size_t)(bn * 128) * DMODEL + k8 * 8;

    const int quad = lane >> 4;
    const int col  = lane & 15;

    for (int k0 = 0; k0 < DMODEL; k0 += 64) {
        #pragma unroll
        for (int it = 0; it < 4; ++it) {
            const int row   = row0 + it * 32;
            const int chunk = it * 256 + tid;
            load_lds16(xg + (size_t)row * DMODEL + k0, &As[chunk * 8]);
            load_lds16(zg + (size_t)row * DMODEL + k0, &Zs[chunk * 8]);
            load_lds16(hg + (size_t)row * DMODEL + k0, &Hs[chunk * 8]);
        }
        __syncthreads();

        #pragma unroll
        for (int kk = 0; kk < 2; ++kk) {
            const int kb = kk * 32 + quad * 8;
            bf16x8 af[4], zf[4], hf[4];
            #pragma unroll
            for (int i = 0; i < 4; ++i) {
                const int am  = wm * 64 + i * 16 + col;
                const int bnr = wn * 64 + i * 16 + col;
                af[i] = *(const bf16x8*)&As[am * 64 + kb];
                zf[i] = *(const bf16x8*)&Zs[bnr * 64 + kb];
                hf[i] = *(const bf16x8*)&Hs[bnr * 64 + kb];
            }
            #pragma unroll
            for (int i = 0; i < 4; ++i)
                #pragma unroll
                for (int j = 0; j < 4; ++j) {
                    accz[i][j] = __builtin_amdgcn_mfma_f32_16x16x32_bf16(af[i], zf[j], accz[i][j], 0, 0, 0);
                    acch[i][j] = __builtin_amdgcn_mfma_f32_16x16x32_bf16(af[i], hf[j], acch[i][j], 0, 0, 0);
                }
        }
        __syncthreads();
    }

    #pragma unroll
    for (int j = 0; j < 4; ++j) {
        const int n = bn * 128 + wn * 64 + j * 16 + col;
        const float bzv = bz[n];
        const float bhv = bh[n];
        #pragma unroll
        for (int i = 0; i < 4; ++i) {
            const int mbase = bm * 128 + wm * 64 + i * 16 + quad * 4;
            #pragma unroll
            for (int r = 0; r < 4; ++r) {
                const float zpre = accz[i][j][r] + bzv;
                const float hpre = acch[i][j][r] + bhv;
                const float z = 1.f / (1.f + __expf(-zpre));
                const float a = 1.f - z;
                const float b = z * hpre;
                const size_t idx = (size_t)(mbase + r) * DMODEL + n;
                ab_ws[idx] = (unsigned)f2bf(a) | ((unsigned)f2bf(b) << 16);
            }
        }
    }
}

// ---------------------------------------------------------------------------
// Scan phases as device functions (shared by coop-fused and fallback paths).
// Layouts: ab_ws[t][h] u32-packed bf16 (a,b); Aagg/Bagg/Hpre [c][h]; states
// [t][h] bf16 bits. LDS use: 4 KB (sA+sB in phase 2 only).
// ---------------------------------------------------------------------------
__device__ __forceinline__ void phase1_body(
    const unsigned int* __restrict__ ab_ws,
    float* __restrict__ Aagg, float* __restrict__ Bagg, int c, int h)
{
    const size_t base = (size_t)(c * LCHUNK) * DMODEL + h;
    float A = 1.f, B = 0.f;
    #pragma unroll 8
    for (int i = 0; i < LCHUNK; ++i) {
        const unsigned u = ab_ws[base + (size_t)i * DMODEL];
        const float a = bf2f((unsigned short)(u & 0xFFFFu));
        const float b = bf2f((unsigned short)(u >> 16));
        A = a * A;
        B = a * B + b;
    }
    Aagg[(size_t)c * DMODEL + h] = A;   // coalesced
    Bagg[(size_t)c * DMODEL + h] = B;
}

__device__ __forceinline__ void phase2_body(
    const float* __restrict__ Aagg, const float* __restrict__ Bagg,
    float* __restrict__ Hpre, float* sA, float* sB, int h, int c)
{
    // block = channel h, thread = chunk c. Column reads are strided but the
    // whole Aagg/Bagg working set is 2 MB (L2/L3-resident).
    float A = Aagg[(size_t)c * DMODEL + h];
    float B = Bagg[(size_t)c * DMODEL + h];
    sA[c] = A; sB[c] = B;
    __syncthreads();
    for (int off = 1; off < NCHUNK; off <<= 1) {
        float pA = 1.f, pB = 0.f;
        if (c >= off) { pA = sA[c - off]; pB = sB[c - off]; }
        __syncthreads();
        const float nB = A * pB + B;   // uses old A
        const float nA = A * pA;
        A = nA; B = nB;
        sA[c] = A; sB[c] = B;
        __syncthreads();
    }
    const float hp = (c == 0) ? 0.f : sB[c - 1];
    Hpre[(size_t)c * DMODEL + h] = hp;
}

__device__ __forceinline__ void phase3_body(
    const unsigned int* __restrict__ ab_ws, const float* __restrict__ Hpre,
    unsigned short* __restrict__ states, int c, int h)
{
    float H = Hpre[(size_t)c * DMODEL + h];  // coalesced
    const size_t base = (size_t)(c * LCHUNK) * DMODEL + h;
    #pragma unroll 8
    for (int i = 0; i < LCHUNK; ++i) {
        const unsigned u = ab_ws[base + (size_t)i * DMODEL];
        const float a = bf2f((unsigned short)(u & 0xFFFFu));
        const float b = bf2f((unsigned short)(u >> 16));
        H = a * H + b;
        states[base + (size_t)i * DMODEL] = f2bf(H);
    }
}

// ---------------------------------------------------------------------------
// Kernel 2 (cooperative): full scan in one launch. grid = 512 x 512 threads.
// Resources: 4 KB LDS, low VGPR -> >=4 blocks/CU capacity, 512 co-resident OK.
// ---------------------------------------------------------------------------
__global__ __launch_bounds__(512, 4) void scan_fused(
    const unsigned int* __restrict__ ab_ws,
    float* __restrict__ Aagg, float* __restrict__ Bagg,
    float* __restrict__ Hpre, unsigned short* __restrict__ states)
{
    cg::grid_group grid = cg::this_grid();
    __shared__ float sA[NCHUNK], sB[NCHUNK];
    const int tid = threadIdx.x;
    const int blk = blockIdx.x;

    phase1_body(ab_ws, Aagg, Bagg, blk, tid);          // block=chunk, thr=chan
    grid.sync();
    phase2_body(Aagg, Bagg, Hpre, sA, sB, blk, tid);   // block=chan, thr=chunk
    grid.sync();
    phase3_body(ab_ws, Hpre, states, blk, tid);        // block=chunk, thr=chan
}

// Fallback (non-coop) versions — launched only if coop enqueue fails.
__global__ __launch_bounds__(512) void scan_p1(
    const unsigned int* __restrict__ ab_ws, float* __restrict__ Aagg, float* __restrict__ Bagg)
{ phase1_body(ab_ws, Aagg, Bagg, blockIdx.x, threadIdx.x); }

__global__ __launch_bounds__(512) void scan_p2(
    const float* __restrict__ Aagg, const float* __restrict__ Bagg, float* __restrict__ Hpre)
{
    __shared__ float sA[NCHUNK], sB[NCHUNK];
    phase2_body(Aagg, Bagg, Hpre, sA, sB, blockIdx.x, threadIdx.x);
}

__global__ __launch_bounds__(512) void scan_p3(
    const unsigned int* __restrict__ ab_ws, const float* __restrict__ Hpre,
    unsigned short* __restrict__ states)
{ phase3_body(ab_ws, Hpre, states, blockIdx.x, threadIdx.x); }

// ---------------------------------------------------------------------------
// Kernel 3: out = states @ Wo^T + bo  (fp32 out)
// ---------------------------------------------------------------------------
__global__ __launch_bounds__(256, 2) void gemm_out(
    const bf16* __restrict__ states, const bf16* __restrict__ Wo, const float* __restrict__ bo,
    float* __restrict__ out)
{
    __shared__ __bf16 As[128 * 64];
    __shared__ __bf16 Bs[128 * 64];

    const int tid  = threadIdx.x;
    const int bn   = blockIdx.x;
    const int bm   = blockIdx.y;
    const int lane = tid & 63;
    const int wave = tid >> 6;
    const int wm   = wave >> 1;
    const int wn   = wave & 1;

    f32x4 acc[4][4];
    #pragma unroll
    for (int i = 0; i < 4; ++i)
        #pragma unroll
        for (int j = 0; j < 4; ++j)
            acc[i][j] = (f32x4){0.f, 0.f, 0.f, 0.f};

    const int row0 = tid >> 3;
    const int k8   = tid & 7;

    const bf16* ag = states + (size_t)(bm * 128) * DMODEL + k8 * 8;
    const bf16* bg = Wo     + (size_t)(bn * 128) * DMODEL + k8 * 8;

    const int quad = lane >> 4;
    const int col  = lane & 15;

    for (int k0 = 0; k0 < DMODEL; k0 += 64) {
        #pragma unroll
        for (int it = 0; it < 4; ++it) {
            const int row   = row0 + it * 32;
            const int chunk = it * 256 + tid;
            load_lds16(ag + (size_t)row * DMODEL + k0, &As[chunk * 8]);
            load_lds16(bg + (size_t)row * DMODEL + k0, &Bs[chunk * 8]);
        }
        __syncthreads();

        #pragma unroll
        for (int kk = 0; kk < 2; ++kk) {
            const int kb = kk * 32 + quad * 8;
            bf16x8 af[4], bf[4];
            #pragma unroll
            for (int i = 0; i < 4; ++i) {
                af[i] = *(const bf16x8*)&As[(wm * 64 + i * 16 + col) * 64 + kb];
                bf[i] = *(const bf16x8*)&Bs[(wn * 64 + i * 16 + col) * 64 + kb];
            }
            #pragma unroll
            for (int i = 0; i < 4; ++i)
                #pragma unroll
                for (int j = 0; j < 4; ++j)
                    acc[i][j] = __builtin_amdgcn_mfma_f32_16x16x32_bf16(af[i], bf[j], acc[i][j], 0, 0, 0);
        }
        __syncthreads();
    }

    #pragma unroll
    for (int j = 0; j < 4; ++j) {
        const int n = bn * 128 + wn * 64 + j * 16 + col;
        const float bov = bo[n];
        #pragma unroll
        for (int i = 0; i < 4; ++i) {
            const int mbase = bm * 128 + wm * 64 + i * 16 + quad * 4;
            #pragma unroll
            for (int r = 0; r < 4; ++r)
                out[(size_t)(mbase + r) * DMODEL + n] = acc[i][j][r] + bov;
        }
    }
}

// ---------------------------------------------------------------------------
extern "C" void kernel_launch(void* const* d_in, const int* in_sizes, int n_in,
                              void* d_out, int out_size, void* d_ws, size_t ws_size,
                              hipStream_t stream)
{
    const float* xs = (const float*)d_in[0];
    const float* Wz = (const float*)d_in[1];
    const float* bz = (const float*)d_in[2];
    const float* Wh = (const float*)d_in[3];
    const float* bh = (const float*)d_in[4];
    const float* Wo = (const float*)d_in[5];
    const float* bo = (const float*)d_in[6];
    float* out = (float*)d_out;

    char* w = (char*)d_ws;
    bf16*  xs_c   = (bf16*) (w);                     // 16,777,216
    bf16*  Wz_c   = (bf16*) (w + 16777216ull);       //    524,288
    bf16*  Wh_c   = (bf16*) (w + 17301504ull);       //    524,288
    bf16*  Wo_c   = (bf16*) (w + 17825792ull);       //    524,288
    unsigned int*   ab_ws  = (unsigned int*)  (w + 18350080ull); // 33,554,432
    unsigned short* states = (unsigned short*)(w + 51904512ull); // 16,777,216
    float* Aagg   = (float*)(w + 68681728ull);       //  1,048,576
    float* Bagg   = (float*)(w + 69730304ull);       //  1,048,576
    float* Hpre   = (float*)(w + 70778880ull);       //  1,048,576

    k_convert<<<(N4_TOT + 255) / 256, 256, 0, stream>>>(xs, Wz, Wh, Wo, xs_c, Wz_c, Wh_c, Wo_c);
    gemm_zh<<<dim3(4, 128), 256, 0, stream>>>(xs_c, Wz_c, bz, Wh_c, bh, ab_ws);

    void* args[] = { (void*)&ab_ws, (void*)&Aagg, (void*)&Bagg, (void*)&Hpre, (void*)&states };
    hipError_t ce = hipLaunchCooperativeKernel((void*)scan_fused, dim3(NCHUNK), dim3(512),
                                               args, 0, stream);
    if (ce != hipSuccess) {
        // deterministic fallback (same decision every call): 3 plain kernels
        scan_p1<<<NCHUNK, 512, 0, stream>>>(ab_ws, Aagg, Bagg);
        scan_p2<<<DMODEL, 512, 0, stream>>>(Aagg, Bagg, Hpre);
        scan_p3<<<NCHUNK, 512, 0, stream>>>(ab_ws, Hpre, states);
    }

    gemm_out<<<dim3(4, 128), 256, 0, stream>>>((const bf16*)states, Wo_c, bo, out);
}

// Round 6
// 152.321 us; speedup vs baseline: 1.8913x; 1.8913x over previous
//
#include <hip/hip_runtime.h>
#include <hip/hip_bf16.h>
#include <cstdint>
#include <cmath>

// Problem constants — inputs/outputs are fp32 (verified R1 vs R2).
// LESSON (R5): hipLaunchCooperativeKernel grid.sync() costs ~50 us on MI355X
// (cross-XCD barrier) — use kernel-boundary barriers instead.
#define T_SEQ 16384
#define DMODEL 512
#define NCHUNK 512        // scan chunks (= T_SEQ/LCHUNK)
#define LCHUNK 32
#define XS_N   (T_SEQ * DMODEL)
#define W_N    (DMODEL * DMODEL)
#define N4_XS  (XS_N / 4)
#define N4_W   (W_N / 4)
#define N4_TOT (N4_XS + 3 * N4_W)

typedef __bf16 bf16x8 __attribute__((ext_vector_type(8)));
typedef float  f32x4  __attribute__((ext_vector_type(4)));

using bf16 = __hip_bfloat16;

__device__ __forceinline__ void load_lds16(const void* g, void* l) {
    __builtin_amdgcn_global_load_lds((const __attribute__((address_space(1))) void*)g,
                                     (__attribute__((address_space(3))) void*)l,
                                     16, 0, 0);
}

__device__ __forceinline__ unsigned short f2bf(float f) {
    union { float f; unsigned u; } v; v.f = f;
    const unsigned r = (v.u + 0x7FFFu + ((v.u >> 16) & 1u)) >> 16;
    return (unsigned short)r;
}
__device__ __forceinline__ float bf2f(unsigned short u) {
    union { unsigned u; float f; } v; v.u = ((unsigned)u) << 16;
    return v.f;
}

// ordered pair-combine: first=(fA,fB) then second=(sA,sB)
// result: A = fA*sA, B = sA*fB + sB
__device__ __forceinline__ void comb(float& A, float& B, float fA, float fB,
                                     float sA, float sB) {
    A = fA * sA;
    B = sA * fB + sB;
}

// ---------------------------------------------------------------------------
// Kernel 0: convert xs, Wz, Wh, Wo fp32 -> bf16 (vectorized x4)
// ---------------------------------------------------------------------------
__global__ __launch_bounds__(256) void k_convert(
    const float* __restrict__ xs, const float* __restrict__ Wz,
    const float* __restrict__ Wh, const float* __restrict__ Wo,
    bf16* __restrict__ xs_c, bf16* __restrict__ Wz_c,
    bf16* __restrict__ Wh_c, bf16* __restrict__ Wo_c)
{
    const int i = blockIdx.x * 256 + threadIdx.x;
    if (i >= N4_TOT) return;
    const float* src;
    bf16* dst;
    int o;
    if (i < N4_XS) { src = xs; dst = xs_c; o = i; }
    else {
        const int j = i - N4_XS;
        const int w = j >> 16;
        o = j & 65535;
        src = (w == 0) ? Wz : (w == 1) ? Wh : Wo;
        dst = (w == 0) ? Wz_c : (w == 1) ? Wh_c : Wo_c;
    }
    const float4 v = ((const float4*)src)[o];
    ushort4 r;
    r.x = f2bf(v.x); r.y = f2bf(v.y); r.z = f2bf(v.z); r.w = f2bf(v.w);
    ((ushort4*)dst)[o] = r;
}

// ---------------------------------------------------------------------------
// Kernel 1: fused dual GEMM + scan phase 1.
// zpre = xs@Wz^T, hpre = xs@Wh^T; a = 1-sigmoid(zpre+bz), b = sig*(hpre+bh).
// Epilogue packs (a,b) bf16 -> ab_ws AND computes per-chunk scan aggregates
// (fp32) via r-serial + quad-shuffle + i-pair ordered combines -> Aagg/Bagg.
// Block rows = 4 chunks of 32 (chunk c = bm*4 + wm*2 + {0,1}).
// grid dim3(128,4): bm fast axis -> same-bn blocks round-robin XCDs (W in L2).
// ---------------------------------------------------------------------------
__global__ __launch_bounds__(256, 2) void gemm_zh(
    const bf16* __restrict__ xs, const bf16* __restrict__ Wz, const float* __restrict__ bz,
    const bf16* __restrict__ Wh, const float* __restrict__ bh,
    unsigned int* __restrict__ ab_ws,
    float* __restrict__ Aagg, float* __restrict__ Bagg)
{
    __shared__ __bf16 As[128 * 64];
    __shared__ __bf16 Zs[128 * 64];
    __shared__ __bf16 Hs[128 * 64];

    const int tid  = threadIdx.x;
    const int bm   = blockIdx.x;   // 0..127 (M tile)
    const int bn   = blockIdx.y;   // 0..3   (N tile)
    const int lane = tid & 63;
    const int wave = tid >> 6;
    const int wm   = wave >> 1;
    const int wn   = wave & 1;

    f32x4 accz[4][4], acch[4][4];
    #pragma unroll
    for (int i = 0; i < 4; ++i)
        #pragma unroll
        for (int j = 0; j < 4; ++j) {
            accz[i][j] = (f32x4){0.f, 0.f, 0.f, 0.f};
            acch[i][j] = (f32x4){0.f, 0.f, 0.f, 0.f};
        }

    const int row0 = tid >> 3;
    const int k8   = tid & 7;

    const bf16* xg = xs + (size_t)(bm * 128) * DMODEL + k8 * 8;
    const bf16* zg = Wz + (size_t)(bn * 128) * DMODEL + k8 * 8;
    const bf16* hg = Wh + (size_t)(bn * 128) * DMODEL + k8 * 8;

    const int quad = lane >> 4;
    const int col  = lane & 15;

    for (int k0 = 0; k0 < DMODEL; k0 += 64) {
        #pragma unroll
        for (int it = 0; it < 4; ++it) {
            const int row   = row0 + it * 32;
            const int chunk = it * 256 + tid;
            load_lds16(xg + (size_t)row * DMODEL + k0, &As[chunk * 8]);
            load_lds16(zg + (size_t)row * DMODEL + k0, &Zs[chunk * 8]);
            load_lds16(hg + (size_t)row * DMODEL + k0, &Hs[chunk * 8]);
        }
        __syncthreads();

        #pragma unroll
        for (int kk = 0; kk < 2; ++kk) {
            const int kb = kk * 32 + quad * 8;
            bf16x8 af[4], zf[4], hf[4];
            #pragma unroll
            for (int i = 0; i < 4; ++i) {
                const int am  = wm * 64 + i * 16 + col;
                const int bnr = wn * 64 + i * 16 + col;
                af[i] = *(const bf16x8*)&As[am * 64 + kb];
                zf[i] = *(const bf16x8*)&Zs[bnr * 64 + kb];
                hf[i] = *(const bf16x8*)&Hs[bnr * 64 + kb];
            }
            #pragma unroll
            for (int i = 0; i < 4; ++i)
                #pragma unroll
                for (int j = 0; j < 4; ++j) {
                    accz[i][j] = __builtin_amdgcn_mfma_f32_16x16x32_bf16(af[i], zf[j], accz[i][j], 0, 0, 0);
                    acch[i][j] = __builtin_amdgcn_mfma_f32_16x16x32_bf16(af[i], hf[j], acch[i][j], 0, 0, 0);
                }
        }
        __syncthreads();
    }

    // epilogue: D layout col=lane&15 (n), row=quad*4+reg (m)
    const int c_lo = bm * 4 + wm * 2;   // chunk of rows [wm*64, wm*64+32)
    #pragma unroll
    for (int j = 0; j < 4; ++j) {
        const int n = bn * 128 + wn * 64 + j * 16 + col;
        const float bzv = bz[n];
        const float bhv = bh[n];
        float cA[4], cB[4];             // per-i 4-row aggregates (rows i*16+quad*4+r)
        #pragma unroll
        for (int i = 0; i < 4; ++i) {
            const int mbase = bm * 128 + wm * 64 + i * 16 + quad * 4;
            float A = 1.f, B = 0.f;
            #pragma unroll
            for (int r = 0; r < 4; ++r) {
                const float zpre = accz[i][j][r] + bzv;
                const float hpre = acch[i][j][r] + bhv;
                const float z = 1.f / (1.f + __expf(-zpre));
                const float a = 1.f - z;
                const float b = z * hpre;
                const size_t idx = (size_t)(mbase + r) * DMODEL + n;
                ab_ws[idx] = (unsigned)f2bf(a) | ((unsigned)f2bf(b) << 16);
                // r ascending == t ascending: A = a*A; B = a*B + b
                A = a * A;
                B = a * B + b;
            }
            cA[i] = A; cB[i] = B;
        }
        // cross-quad ordered combine (rows quad*4.. within each i*16 group)
        #pragma unroll
        for (int i = 0; i < 4; ++i) {
            float pA = __shfl_xor(cA[i], 16);
            float pB = __shfl_xor(cB[i], 16);
            const bool hi1 = quad & 1;
            comb(cA[i], cB[i], hi1 ? pA : cA[i], hi1 ? pB : cB[i],
                               hi1 ? cA[i] : pA, hi1 ? cB[i] : pB);
            pA = __shfl_xor(cA[i], 32);
            pB = __shfl_xor(cB[i], 32);
            const bool hi2 = quad >> 1;
            comb(cA[i], cB[i], hi2 ? pA : cA[i], hi2 ? pB : cB[i],
                               hi2 ? cA[i] : pA, hi2 ? cB[i] : pB);
        }
        // i-pairs: chunk_lo = rows 0..31 (i0 then i1), chunk_hi = rows 32..63
        float Alo, Blo, Ahi, Bhi;
        comb(Alo, Blo, cA[0], cB[0], cA[1], cB[1]);
        comb(Ahi, Bhi, cA[2], cB[2], cA[3], cB[3]);
        if (quad == 0) {                 // 16 lanes store 16 consecutive n
            Aagg[(size_t)c_lo * DMODEL + n]       = Alo;
            Bagg[(size_t)c_lo * DMODEL + n]       = Blo;
            Aagg[(size_t)(c_lo + 1) * DMODEL + n] = Ahi;
            Bagg[(size_t)(c_lo + 1) * DMODEL + n] = Bhi;
        }
    }
}

// ---------------------------------------------------------------------------
// Kernel 2: per-channel Hillis-Steele over NCHUNK chunk aggregates.
// grid = 512 channel-blocks x 512 threads (thread = chunk). 4 KB LDS.
// ---------------------------------------------------------------------------
__global__ __launch_bounds__(512) void scan_p2(
    const float* __restrict__ Aagg, const float* __restrict__ Bagg,
    float* __restrict__ Hpre)
{
    const int h = blockIdx.x;
    const int c = threadIdx.x;
    __shared__ float sA[NCHUNK], sB[NCHUNK];

    float A = Aagg[(size_t)c * DMODEL + h];
    float B = Bagg[(size_t)c * DMODEL + h];
    sA[c] = A; sB[c] = B;
    __syncthreads();

    for (int off = 1; off < NCHUNK; off <<= 1) {
        float pA = 1.f, pB = 0.f;
        if (c >= off) { pA = sA[c - off]; pB = sB[c - off]; }
        __syncthreads();
        const float nB = A * pB + B;   // uses old A
        const float nA = A * pA;
        A = nA; B = nB;
        sA[c] = A; sB[c] = B;
        __syncthreads();
    }
    const float hp = (c == 0) ? 0.f : sB[c - 1];
    Hpre[(size_t)c * DMODEL + h] = hp;
}

// ---------------------------------------------------------------------------
// Kernel 3: replay chunk recurrence from Hpre; write bf16 states.
// grid = 512 chunk-blocks x 256 threads; thread = 2 channels (uint2 loads).
// ---------------------------------------------------------------------------
__global__ __launch_bounds__(256) void scan_p3(
    const unsigned int* __restrict__ ab_ws, const float* __restrict__ Hpre,
    unsigned short* __restrict__ states)
{
    const int tid = threadIdx.x;           // channel pair
    const int c   = blockIdx.x;
    const float2 hp = ((const float2*)(Hpre + (size_t)c * DMODEL))[tid];
    float H0 = hp.x, H1 = hp.y;
    const size_t rowbase = (size_t)(c * LCHUNK) * DMODEL;
    #pragma unroll 8
    for (int i = 0; i < LCHUNK; ++i) {
        const size_t row = rowbase + (size_t)i * DMODEL;
        const uint2 u = ((const uint2*)(ab_ws + row))[tid];
        const float a0 = bf2f((unsigned short)(u.x & 0xFFFFu));
        const float b0 = bf2f((unsigned short)(u.x >> 16));
        const float a1 = bf2f((unsigned short)(u.y & 0xFFFFu));
        const float b1 = bf2f((unsigned short)(u.y >> 16));
        H0 = a0 * H0 + b0;
        H1 = a1 * H1 + b1;
        ushort2 s; s.x = f2bf(H0); s.y = f2bf(H1);
        ((ushort2*)(states + row))[tid] = s;
    }
}

// ---------------------------------------------------------------------------
// Kernel 4: out = states @ Wo^T + bo  (fp32 out). grid dim3(128,4), bm fast.
// ---------------------------------------------------------------------------
__global__ __launch_bounds__(256, 2) void gemm_out(
    const bf16* __restrict__ states, const bf16* __restrict__ Wo, const float* __restrict__ bo,
    float* __restrict__ out)
{
    __shared__ __bf16 As[128 * 64];
    __shared__ __bf16 Bs[128 * 64];

    const int tid  = threadIdx.x;
    const int bm   = blockIdx.x;
    const int bn   = blockIdx.y;
    const int lane = tid & 63;
    const int wave = tid >> 6;
    const int wm   = wave >> 1;
    const int wn   = wave & 1;

    f32x4 acc[4][4];
    #pragma unroll
    for (int i = 0; i < 4; ++i)
        #pragma unroll
        for (int j = 0; j < 4; ++j)
            acc[i][j] = (f32x4){0.f, 0.f, 0.f, 0.f};

    const int row0 = tid >> 3;
    const int k8   = tid & 7;

    const bf16* ag = states + (size_t)(bm * 128) * DMODEL + k8 * 8;
    const bf16* bg = Wo     + (size_t)(bn * 128) * DMODEL + k8 * 8;

    const int quad = lane >> 4;
    const int col  = lane & 15;

    for (int k0 = 0; k0 < DMODEL; k0 += 64) {
        #pragma unroll
        for (int it = 0; it < 4; ++it) {
            const int row   = row0 + it * 32;
            const int chunk = it * 256 + tid;
            load_lds16(ag + (size_t)row * DMODEL + k0, &As[chunk * 8]);
            load_lds16(bg + (size_t)row * DMODEL + k0, &Bs[chunk * 8]);
        }
        __syncthreads();

        #pragma unroll
        for (int kk = 0; kk < 2; ++kk) {
            const int kb = kk * 32 + quad * 8;
            bf16x8 af[4], bf[4];
            #pragma unroll
            for (int i = 0; i < 4; ++i) {
                af[i] = *(const bf16x8*)&As[(wm * 64 + i * 16 + col) * 64 + kb];
                bf[i] = *(const bf16x8*)&Bs[(wn * 64 + i * 16 + col) * 64 + kb];
            }
            #pragma unroll
            for (int i = 0; i < 4; ++i)
                #pragma unroll
                for (int j = 0; j < 4; ++j)
                    acc[i][j] = __builtin_amdgcn_mfma_f32_16x16x32_bf16(af[i], bf[j], acc[i][j], 0, 0, 0);
        }
        __syncthreads();
    }

    #pragma unroll
    for (int j = 0; j < 4; ++j) {
        const int n = bn * 128 + wn * 64 + j * 16 + col;
        const float bov = bo[n];
        #pragma unroll
        for (int i = 0; i < 4; ++i) {
            const int mbase = bm * 128 + wm * 64 + i * 16 + quad * 4;
            #pragma unroll
            for (int r = 0; r < 4; ++r)
                out[(size_t)(mbase + r) * DMODEL + n] = acc[i][j][r] + bov;
        }
    }
}

// ---------------------------------------------------------------------------
extern "C" void kernel_launch(void* const* d_in, const int* in_sizes, int n_in,
                              void* d_out, int out_size, void* d_ws, size_t ws_size,
                              hipStream_t stream)
{
    const float* xs = (const float*)d_in[0];
    const float* Wz = (const float*)d_in[1];
    const float* bz = (const float*)d_in[2];
    const float* Wh = (const float*)d_in[3];
    const float* bh = (const float*)d_in[4];
    const float* Wo = (const float*)d_in[5];
    const float* bo = (const float*)d_in[6];
    float* out = (float*)d_out;

    char* w = (char*)d_ws;
    bf16*  xs_c   = (bf16*) (w);                     // 16,777,216
    bf16*  Wz_c   = (bf16*) (w + 16777216ull);       //    524,288
    bf16*  Wh_c   = (bf16*) (w + 17301504ull);       //    524,288
    bf16*  Wo_c   = (bf16*) (w + 17825792ull);       //    524,288
    unsigned int*   ab_ws  = (unsigned int*)  (w + 18350080ull); // 33,554,432
    unsigned short* states = (unsigned short*)(w + 51904512ull); // 16,777,216
    float* Aagg   = (float*)(w + 68681728ull);       //  1,048,576
    float* Bagg   = (float*)(w + 69730304ull);       //  1,048,576
    float* Hpre   = (float*)(w + 70778880ull);       //  1,048,576

    k_convert<<<(N4_TOT + 255) / 256, 256, 0, stream>>>(xs, Wz, Wh, Wo, xs_c, Wz_c, Wh_c, Wo_c);
    gemm_zh<<<dim3(128, 4), 256, 0, stream>>>(xs_c, Wz_c, bz, Wh_c, bh, ab_ws, Aagg, Bagg);
    scan_p2<<<DMODEL, NCHUNK, 0, stream>>>(Aagg, Bagg, Hpre);
    scan_p3<<<NCHUNK, 256, 0, stream>>>(ab_ws, Hpre, states);
    gemm_out<<<dim3(128, 4), 256, 0, stream>>>((const bf16*)states, Wo_c, bo, out);
}

// Round 7
// 151.846 us; speedup vs baseline: 1.8972x; 1.0031x over previous
//
#include <hip/hip_runtime.h>
#include <hip/hip_bf16.h>
#include <cstdint>
#include <cmath>

// Problem constants — inputs/outputs are fp32 (verified R1 vs R2).
// LESSON (R5): cooperative grid.sync() costs ~50 us on MI355X — use kernel
// boundaries. LESSON (R6): scan topology is cheap; convert + GEMM staging and
// scatter patterns are the fat.
#define T_SEQ 16384
#define DMODEL 512
#define NCHUNK 512        // scan chunks (= T_SEQ/LCHUNK)
#define LCHUNK 32
#define W_N    (DMODEL * DMODEL)
#define N4_W   (W_N / 4)
#define N4_W3  (3 * N4_W)

typedef __bf16 bf16x8 __attribute__((ext_vector_type(8)));
typedef float  f32x4  __attribute__((ext_vector_type(4)));

using bf16 = __hip_bfloat16;

__device__ __forceinline__ void load_lds16(const void* g, void* l) {
    __builtin_amdgcn_global_load_lds((const __attribute__((address_space(1))) void*)g,
                                     (__attribute__((address_space(3))) void*)l,
                                     16, 0, 0);
}

__device__ __forceinline__ unsigned short f2bf(float f) {
    union { float f; unsigned u; } v; v.f = f;
    const unsigned r = (v.u + 0x7FFFu + ((v.u >> 16) & 1u)) >> 16;
    return (unsigned short)r;
}
__device__ __forceinline__ float bf2f(unsigned short u) {
    union { unsigned u; float f; } v; v.u = ((unsigned)u) << 16;
    return v.f;
}

// ordered pair-combine: first=(fA,fB) then second=(sA,sB)
__device__ __forceinline__ void comb(float& A, float& B, float fA, float fB,
                                     float sA, float sB) {
    A = fA * sA;
    B = sA * fB + sB;
}

// ---------------------------------------------------------------------------
// Kernel 0: convert Wz, Wh, Wo fp32 -> bf16 (weights only; xs fused into
// gemm_zh staging). 3 MB total.
// ---------------------------------------------------------------------------
__global__ __launch_bounds__(256) void k_convert_w(
    const float* __restrict__ Wz, const float* __restrict__ Wh,
    const float* __restrict__ Wo,
    bf16* __restrict__ Wz_c, bf16* __restrict__ Wh_c, bf16* __restrict__ Wo_c)
{
    const int i = blockIdx.x * 256 + threadIdx.x;
    if (i >= N4_W3) return;
    const int w = i >> 16;
    const int o = i & 65535;
    const float* src = (w == 0) ? Wz : (w == 1) ? Wh : Wo;
    bf16* dst = (w == 0) ? Wz_c : (w == 1) ? Wh_c : Wo_c;
    const float4 v = ((const float4*)src)[o];
    ushort4 r;
    r.x = f2bf(v.x); r.y = f2bf(v.y); r.z = f2bf(v.z); r.w = f2bf(v.w);
    ((ushort4*)dst)[o] = r;
}

// ---------------------------------------------------------------------------
// Kernel 1: fused dual GEMM + scan phase 1.
// xs is read as fp32 and converted to bf16 during LDS staging (register path).
// Epilogue packs (a,b) bf16 -> ab_ws and writes per-chunk aggregates
// TRANSPOSED ([h][c], scattered fire-and-forget) -> AaggT/BaggT.
// ---------------------------------------------------------------------------
__global__ __launch_bounds__(256, 2) void gemm_zh(
    const float* __restrict__ xs, const bf16* __restrict__ Wz, const float* __restrict__ bz,
    const bf16* __restrict__ Wh, const float* __restrict__ bh,
    unsigned int* __restrict__ ab_ws,
    float* __restrict__ AaggT, float* __restrict__ BaggT)
{
    __shared__ __bf16 As[128 * 64];
    __shared__ __bf16 Zs[128 * 64];
    __shared__ __bf16 Hs[128 * 64];

    const int tid  = threadIdx.x;
    const int bm   = blockIdx.x;   // 0..127 (M tile)
    const int bn   = blockIdx.y;   // 0..3   (N tile)
    const int lane = tid & 63;
    const int wave = tid >> 6;
    const int wm   = wave >> 1;
    const int wn   = wave & 1;

    f32x4 accz[4][4], acch[4][4];
    #pragma unroll
    for (int i = 0; i < 4; ++i)
        #pragma unroll
        for (int j = 0; j < 4; ++j) {
            accz[i][j] = (f32x4){0.f, 0.f, 0.f, 0.f};
            acch[i][j] = (f32x4){0.f, 0.f, 0.f, 0.f};
        }

    // W staging (bf16, global_load_lds): 1024 chunks of 16B per tile
    const int row0 = tid >> 3;       // +32 per it
    const int k8   = tid & 7;
    const bf16* zg = Wz + (size_t)(bn * 128) * DMODEL + k8 * 8;
    const bf16* hg = Wh + (size_t)(bn * 128) * DMODEL + k8 * 8;

    // xs staging (fp32 -> bf16 register path): 2048 float4 per tile
    const int frow = tid >> 4;       // +16 per it2 (8 its)
    const int f4   = tid & 15;
    const float* xg = xs + ((size_t)(bm * 128) + frow) * DMODEL + f4 * 4;

    const int quad = lane >> 4;
    const int col  = lane & 15;

    for (int k0 = 0; k0 < DMODEL; k0 += 64) {
        #pragma unroll
        for (int it = 0; it < 4; ++it) {
            const int row   = row0 + it * 32;
            const int chunk = it * 256 + tid;
            load_lds16(zg + (size_t)row * DMODEL + k0, &Zs[chunk * 8]);
            load_lds16(hg + (size_t)row * DMODEL + k0, &Hs[chunk * 8]);
        }
        #pragma unroll
        for (int it2 = 0; it2 < 8; ++it2) {
            const int row = frow + it2 * 16;
            const float4 v = *(const float4*)(xg + (size_t)(it2 * 16) * DMODEL + k0);
            __hip_bfloat162 p0 = __float22bfloat162_rn(make_float2(v.x, v.y));
            __hip_bfloat162 p1 = __float22bfloat162_rn(make_float2(v.z, v.w));
            uint2 pk;
            pk.x = *(const unsigned*)&p0;
            pk.y = *(const unsigned*)&p1;
            *(uint2*)&As[row * 64 + f4 * 4] = pk;
        }
        __syncthreads();

        #pragma unroll
        for (int kk = 0; kk < 2; ++kk) {
            const int kb = kk * 32 + quad * 8;
            bf16x8 af[4], zf[4], hf[4];
            #pragma unroll
            for (int i = 0; i < 4; ++i) {
                const int am  = wm * 64 + i * 16 + col;
                const int bnr = wn * 64 + i * 16 + col;
                af[i] = *(const bf16x8*)&As[am * 64 + kb];
                zf[i] = *(const bf16x8*)&Zs[bnr * 64 + kb];
                hf[i] = *(const bf16x8*)&Hs[bnr * 64 + kb];
            }
            #pragma unroll
            for (int i = 0; i < 4; ++i)
                #pragma unroll
                for (int j = 0; j < 4; ++j) {
                    accz[i][j] = __builtin_amdgcn_mfma_f32_16x16x32_bf16(af[i], zf[j], accz[i][j], 0, 0, 0);
                    acch[i][j] = __builtin_amdgcn_mfma_f32_16x16x32_bf16(af[i], hf[j], acch[i][j], 0, 0, 0);
                }
        }
        __syncthreads();
    }

    // epilogue: D layout col=lane&15 (n), row=quad*4+reg (m)
    const int c_lo = bm * 4 + wm * 2;
    #pragma unroll
    for (int j = 0; j < 4; ++j) {
        const int n = bn * 128 + wn * 64 + j * 16 + col;
        const float bzv = bz[n];
        const float bhv = bh[n];
        float cA[4], cB[4];
        #pragma unroll
        for (int i = 0; i < 4; ++i) {
            const int mbase = bm * 128 + wm * 64 + i * 16 + quad * 4;
            float A = 1.f, B = 0.f;
            #pragma unroll
            for (int r = 0; r < 4; ++r) {
                const float zpre = accz[i][j][r] + bzv;
                const float hpre = acch[i][j][r] + bhv;
                const float z = 1.f / (1.f + __expf(-zpre));
                const float a = 1.f - z;
                const float b = z * hpre;
                const size_t idx = (size_t)(mbase + r) * DMODEL + n;
                ab_ws[idx] = (unsigned)f2bf(a) | ((unsigned)f2bf(b) << 16);
                A = a * A;
                B = a * B + b;
            }
            cA[i] = A; cB[i] = B;
        }
        #pragma unroll
        for (int i = 0; i < 4; ++i) {
            float pA = __shfl_xor(cA[i], 16);
            float pB = __shfl_xor(cB[i], 16);
            const bool hi1 = quad & 1;
            comb(cA[i], cB[i], hi1 ? pA : cA[i], hi1 ? pB : cB[i],
                               hi1 ? cA[i] : pA, hi1 ? cB[i] : pB);
            pA = __shfl_xor(cA[i], 32);
            pB = __shfl_xor(cB[i], 32);
            const bool hi2 = quad >> 1;
            comb(cA[i], cB[i], hi2 ? pA : cA[i], hi2 ? pB : cB[i],
                               hi2 ? cA[i] : pA, hi2 ? cB[i] : pB);
        }
        float Alo, Blo, Ahi, Bhi;
        comb(Alo, Blo, cA[0], cB[0], cA[1], cB[1]);
        comb(Ahi, Bhi, cA[2], cB[2], cA[3], cB[3]);
        if (quad == 0) {   // transposed [h][c] stores (scattered, overlapped)
            AaggT[(size_t)n * NCHUNK + c_lo]     = Alo;
            BaggT[(size_t)n * NCHUNK + c_lo]     = Blo;
            AaggT[(size_t)n * NCHUNK + c_lo + 1] = Ahi;
            BaggT[(size_t)n * NCHUNK + c_lo + 1] = Bhi;
        }
    }
}

// ---------------------------------------------------------------------------
// Kernel 2: per-channel Hillis-Steele over NCHUNK chunk aggregates.
// grid = 512 channel-blocks x 512 threads. Fully coalesced r/w via [h][c].
// ---------------------------------------------------------------------------
__global__ __launch_bounds__(512) void scan_p2(
    const float* __restrict__ AaggT, const float* __restrict__ BaggT,
    float* __restrict__ HpreT)
{
    const int h = blockIdx.x;
    const int c = threadIdx.x;
    __shared__ float sA[NCHUNK], sB[NCHUNK];

    float A = AaggT[(size_t)h * NCHUNK + c];
    float B = BaggT[(size_t)h * NCHUNK + c];
    sA[c] = A; sB[c] = B;
    __syncthreads();

    for (int off = 1; off < NCHUNK; off <<= 1) {
        float pA = 1.f, pB = 0.f;
        if (c >= off) { pA = sA[c - off]; pB = sB[c - off]; }
        __syncthreads();
        const float nB = A * pB + B;   // uses old A
        const float nA = A * pA;
        A = nA; B = nB;
        sA[c] = A; sB[c] = B;
        __syncthreads();
    }
    const float hp = (c == 0) ? 0.f : sB[c - 1];
    HpreT[(size_t)h * NCHUNK + c] = hp;
}

// ---------------------------------------------------------------------------
// Kernel 3: replay chunk recurrence from HpreT; write bf16 states.
// grid = 512 chunk-blocks x 256 threads; thread = 2 channels (uint2 loads).
// ---------------------------------------------------------------------------
__global__ __launch_bounds__(256) void scan_p3(
    const unsigned int* __restrict__ ab_ws, const float* __restrict__ HpreT,
    unsigned short* __restrict__ states)
{
    const int tid = threadIdx.x;           // channel pair
    const int c   = blockIdx.x;
    float H0 = HpreT[(size_t)(2 * tid) * NCHUNK + c];       // one-time gather
    float H1 = HpreT[(size_t)(2 * tid + 1) * NCHUNK + c];
    const size_t rowbase = (size_t)(c * LCHUNK) * DMODEL;
    #pragma unroll 8
    for (int i = 0; i < LCHUNK; ++i) {
        const size_t row = rowbase + (size_t)i * DMODEL;
        const uint2 u = ((const uint2*)(ab_ws + row))[tid];
        const float a0 = bf2f((unsigned short)(u.x & 0xFFFFu));
        const float b0 = bf2f((unsigned short)(u.x >> 16));
        const float a1 = bf2f((unsigned short)(u.y & 0xFFFFu));
        const float b1 = bf2f((unsigned short)(u.y >> 16));
        H0 = a0 * H0 + b0;
        H1 = a1 * H1 + b1;
        ushort2 s; s.x = f2bf(H0); s.y = f2bf(H1);
        ((ushort2*)(states + row))[tid] = s;
    }
}

// ---------------------------------------------------------------------------
// Kernel 4: out = states @ Wo^T + bo  (fp32 out). grid dim3(128,4), bm fast.
// ---------------------------------------------------------------------------
__global__ __launch_bounds__(256, 2) void gemm_out(
    const bf16* __restrict__ states, const bf16* __restrict__ Wo, const float* __restrict__ bo,
    float* __restrict__ out)
{
    __shared__ __bf16 As[128 * 64];
    __shared__ __bf16 Bs[128 * 64];

    const int tid  = threadIdx.x;
    const int bm   = blockIdx.x;
    const int bn   = blockIdx.y;
    const int lane = tid & 63;
    const int wave = tid >> 6;
    const int wm   = wave >> 1;
    const int wn   = wave & 1;

    f32x4 acc[4][4];
    #pragma unroll
    for (int i = 0; i < 4; ++i)
        #pragma unroll
        for (int j = 0; j < 4; ++j)
            acc[i][j] = (f32x4){0.f, 0.f, 0.f, 0.f};

    const int row0 = tid >> 3;
    const int k8   = tid & 7;

    const bf16* ag = states + (size_t)(bm * 128) * DMODEL + k8 * 8;
    const bf16* bg = Wo     + (size_t)(bn * 128) * DMODEL + k8 * 8;

    const int quad = lane >> 4;
    const int col  = lane & 15;

    for (int k0 = 0; k0 < DMODEL; k0 += 64) {
        #pragma unroll
        for (int it = 0; it < 4; ++it) {
            const int row   = row0 + it * 32;
            const int chunk = it * 256 + tid;
            load_lds16(ag + (size_t)row * DMODEL + k0, &As[chunk * 8]);
            load_lds16(bg + (size_t)row * DMODEL + k0, &Bs[chunk * 8]);
        }
        __syncthreads();

        #pragma unroll
        for (int kk = 0; kk < 2; ++kk) {
            const int kb = kk * 32 + quad * 8;
            bf16x8 af[4], bf[4];
            #pragma unroll
            for (int i = 0; i < 4; ++i) {
                af[i] = *(const bf16x8*)&As[(wm * 64 + i * 16 + col) * 64 + kb];
                bf[i] = *(const bf16x8*)&Bs[(wn * 64 + i * 16 + col) * 64 + kb];
            }
            #pragma unroll
            for (int i = 0; i < 4; ++i)
                #pragma unroll
                for (int j = 0; j < 4; ++j)
                    acc[i][j] = __builtin_amdgcn_mfma_f32_16x16x32_bf16(af[i], bf[j], acc[i][j], 0, 0, 0);
        }
        __syncthreads();
    }

    #pragma unroll
    for (int j = 0; j < 4; ++j) {
        const int n = bn * 128 + wn * 64 + j * 16 + col;
        const float bov = bo[n];
        #pragma unroll
        for (int i = 0; i < 4; ++i) {
            const int mbase = bm * 128 + wm * 64 + i * 16 + quad * 4;
            #pragma unroll
            for (int r = 0; r < 4; ++r)
                out[(size_t)(mbase + r) * DMODEL + n] = acc[i][j][r] + bov;
        }
    }
}

// ---------------------------------------------------------------------------
extern "C" void kernel_launch(void* const* d_in, const int* in_sizes, int n_in,
                              void* d_out, int out_size, void* d_ws, size_t ws_size,
                              hipStream_t stream)
{
    const float* xs = (const float*)d_in[0];
    const float* Wz = (const float*)d_in[1];
    const float* bz = (const float*)d_in[2];
    const float* Wh = (const float*)d_in[3];
    const float* bh = (const float*)d_in[4];
    const float* Wo = (const float*)d_in[5];
    const float* bo = (const float*)d_in[6];
    float* out = (float*)d_out;

    char* w = (char*)d_ws;
    bf16*  Wz_c   = (bf16*) (w);                     //    524,288
    bf16*  Wh_c   = (bf16*) (w + 524288ull);         //    524,288
    bf16*  Wo_c   = (bf16*) (w + 1048576ull);        //    524,288
    unsigned int*   ab_ws  = (unsigned int*)  (w + 1572864ull);  // 33,554,432
    unsigned short* states = (unsigned short*)(w + 35127296ull); // 16,777,216
    float* AaggT  = (float*)(w + 51904512ull);       //  1,048,576
    float* BaggT  = (float*)(w + 52953088ull);       //  1,048,576
    float* HpreT  = (float*)(w + 54001664ull);       //  1,048,576

    k_convert_w<<<(N4_W3 + 255) / 256, 256, 0, stream>>>(Wz, Wh, Wo, Wz_c, Wh_c, Wo_c);
    gemm_zh<<<dim3(128, 4), 256, 0, stream>>>(xs, Wz_c, bz, Wh_c, bh, ab_ws, AaggT, BaggT);
    scan_p2<<<DMODEL, NCHUNK, 0, stream>>>(AaggT, BaggT, HpreT);
    scan_p3<<<NCHUNK, 256, 0, stream>>>(ab_ws, HpreT, states);
    gemm_out<<<dim3(128, 4), 256, 0, stream>>>((const bf16*)states, Wo_c, bo, out);
}